// Round 1
// baseline (468.728 us; speedup 1.0000x reference)
//
#include <hip/hip_runtime.h>
#include <cstdint>
#include <cstddef>

// ---------------------------------------------------------------------------
// LocallyGroupedAttn (Twins-SVT style windowed MHSA), MI355X / gfx950
// B=8, H=W=112, C=256, ws=7, heads=8, hd=32  ->  no padding (112 % 7 == 0)
// Pipeline: [k_qkv]  x @ qkv_w^T + b  -> bf16 qkv in window-gathered layout
//           [k_attn] per (window,head) 49x49 attention        -> bf16 o
//           [k_proj] o @ proj_w^T + b                          -> f32 out
// All matmuls on bf16 MFMA (fp32 accum); softmax in fp32.
// ---------------------------------------------------------------------------

typedef __attribute__((ext_vector_type(8))) short bf16x8;
typedef __attribute__((ext_vector_type(4))) float f32x4;

#define MFMA_BF16(a, b, c) __builtin_amdgcn_mfma_f32_16x16x32_bf16((a), (b), (c), 0, 0, 0)

__device__ __forceinline__ unsigned short f2bf(float f) {
  unsigned int u = __builtin_bit_cast(unsigned int, f);
  u += 0x7fffu + ((u >> 16) & 1u);          // round-to-nearest-even
  return (unsigned short)(u >> 16);
}

#define LDA 40  // LDS row stride in bf16 elems: 80 B = 5*16 B (b128-aligned, ~2-way banks = free)

// ---------------------------------------------------------------------------
// Kernel 1: qkv = x @ qkv_w^T + qkv_b, scattered to [b][win][3][h][49][32] bf16
// Tiles: BM=128, BN=128, BK=32, K=256. 256 thr = 4 waves (2x2 of 64x64).
// ---------------------------------------------------------------------------
__global__ __launch_bounds__(256) void k_qkv(const float* __restrict__ x,
                                             const float* __restrict__ w,
                                             const float* __restrict__ bias,
                                             unsigned short* __restrict__ qkv) {
  __shared__ unsigned short As[2][128 * LDA];
  __shared__ unsigned short Bs[2][128 * LDA];

  // 4704 blocks = 8*588; XCD-bijective swizzle, n-tile fastest within a chunk
  const int id = blockIdx.x;
  const int wg = (id & 7) * 588 + (id >> 3);
  const int mt = wg / 6, nt = wg - mt * 6;
  const int m0 = mt * 128, n0 = nt * 128;

  const int tid = threadIdx.x;
  const int lane = tid & 63, wid = tid >> 6;
  const int wr = (wid >> 1) * 64, wc = (wid & 1) * 64;
  const int l15 = lane & 15, l4 = lane >> 4;

  const int srow = tid >> 3;        // 0..31 (x4 passes -> 128 rows)
  const int skc = (tid & 7) * 4;    // float4 chunk within BK=32

  f32x4 acc[4][4] = {};
  float4 ar[4], br[4];

#pragma unroll
  for (int p = 0; p < 4; ++p) {
    const int row = srow + p * 32;
    ar[p] = *reinterpret_cast<const float4*>(x + (size_t)(m0 + row) * 256 + skc);
    br[p] = *reinterpret_cast<const float4*>(w + (size_t)(n0 + row) * 256 + skc);
  }
#pragma unroll
  for (int p = 0; p < 4; ++p) {
    const int row = srow + p * 32;
    union { unsigned short u[4]; uint2 v; } pa, pb;
    pa.u[0] = f2bf(ar[p].x); pa.u[1] = f2bf(ar[p].y); pa.u[2] = f2bf(ar[p].z); pa.u[3] = f2bf(ar[p].w);
    pb.u[0] = f2bf(br[p].x); pb.u[1] = f2bf(br[p].y); pb.u[2] = f2bf(br[p].z); pb.u[3] = f2bf(br[p].w);
    *reinterpret_cast<uint2*>(&As[0][row * LDA + skc]) = pa.v;
    *reinterpret_cast<uint2*>(&Bs[0][row * LDA + skc]) = pb.v;
  }

  for (int ks = 0; ks < 8; ++ks) {
    __syncthreads();
    const int buf = ks & 1;
    if (ks < 7) {  // T14: issue next-tile global loads before compute
      const int k0 = (ks + 1) * 32;
#pragma unroll
      for (int p = 0; p < 4; ++p) {
        const int row = srow + p * 32;
        ar[p] = *reinterpret_cast<const float4*>(x + (size_t)(m0 + row) * 256 + k0 + skc);
        br[p] = *reinterpret_cast<const float4*>(w + (size_t)(n0 + row) * 256 + k0 + skc);
      }
    }
    bf16x8 af[4], bfr[4];
#pragma unroll
    for (int i = 0; i < 4; ++i) {
      af[i]  = *reinterpret_cast<const bf16x8*>(&As[buf][(wr + i * 16 + l15) * LDA + l4 * 8]);
      bfr[i] = *reinterpret_cast<const bf16x8*>(&Bs[buf][(wc + i * 16 + l15) * LDA + l4 * 8]);
    }
#pragma unroll
    for (int mi = 0; mi < 4; ++mi)
#pragma unroll
      for (int ni = 0; ni < 4; ++ni)
        acc[mi][ni] = MFMA_BF16(af[mi], bfr[ni], acc[mi][ni]);
    if (ks < 7) {  // write-late into the other buffer
#pragma unroll
      for (int p = 0; p < 4; ++p) {
        const int row = srow + p * 32;
        union { unsigned short u[4]; uint2 v; } pa, pb;
        pa.u[0] = f2bf(ar[p].x); pa.u[1] = f2bf(ar[p].y); pa.u[2] = f2bf(ar[p].z); pa.u[3] = f2bf(ar[p].w);
        pb.u[0] = f2bf(br[p].x); pb.u[1] = f2bf(br[p].y); pb.u[2] = f2bf(br[p].z); pb.u[3] = f2bf(br[p].w);
        *reinterpret_cast<uint2*>(&As[buf ^ 1][row * LDA + skc]) = pa.v;
        *reinterpret_cast<uint2*>(&Bs[buf ^ 1][row * LDA + skc]) = pb.v;
      }
    }
  }

  // epilogue: + bias, scatter bf16 into [b][win][3][h][49][32]
  float bv[4]; int whichv[4], hv[4], dv[4];
#pragma unroll
  for (int ni = 0; ni < 4; ++ni) {
    const int ncol = n0 + wc + ni * 16 + l15;
    bv[ni] = bias[ncol];
    whichv[ni] = ncol >> 8; hv[ni] = (ncol >> 5) & 7; dv[ni] = ncol & 31;
  }
#pragma unroll
  for (int mi = 0; mi < 4; ++mi) {
#pragma unroll
    for (int r = 0; r < 4; ++r) {
      const int mrow = m0 + wr + mi * 16 + l4 * 4 + r;
      const int btok = mrow / 12544;
      const int pix = mrow - btok * 12544;
      const int py = pix / 112, px = pix - py * 112;
      const int wy = py / 7, ty = py - wy * 7;
      const int wx = px / 7, tx = px - wx * 7;
      const size_t bw3 = (size_t)(btok * 256 + wy * 16 + wx) * 3;
      const int t = ty * 7 + tx;
#pragma unroll
      for (int ni = 0; ni < 4; ++ni) {
        const float v = acc[mi][ni][r] + bv[ni];
        const size_t dst = (((bw3 + whichv[ni]) * 8 + hv[ni]) * 49 + t) * 32 + dv[ni];
        qkv[dst] = f2bf(v);
      }
    }
  }
}

// ---------------------------------------------------------------------------
// Kernel 2: per (window, head) attention. 1 wave / block, 16384 blocks.
// S = q k^T (16 MFMA), masked wave-parallel softmax, O = P V (16 MFMA).
// ---------------------------------------------------------------------------
__global__ __launch_bounds__(64) void k_attn(const unsigned short* __restrict__ qkv,
                                             unsigned short* __restrict__ o) {
  __shared__ unsigned short vT[32 * 64];   // [d][j] XOR-swizzled, j zero-padded
  __shared__ unsigned short Pl[64 * 64];   // [i][j] XOR-swizzled

  const int lane = threadIdx.x;
  const int l15 = lane & 15, l4 = lane >> 4;

  const int bid = blockIdx.x;
  const int h = bid & 7;
  const int bw = bid >> 3;              // b*256 + win
  const int b = bw >> 8, win = bw & 255;

  const unsigned short* qg = qkv + ((size_t)bw * 24 + h) * 1568;
  const unsigned short* kg = qkv + ((size_t)bw * 24 + 8 + h) * 1568;
  const unsigned short* vg = qkv + ((size_t)bw * 24 + 16 + h) * 1568;

  // stage V transposed, swizzled; zero rows j>=49
  for (int idx = lane; idx < 2048; idx += 64) {
    const int j = idx >> 5, d = idx & 31;
    const unsigned short val = (j < 49) ? vg[j * 32 + d] : (unsigned short)0;
    vT[d * 64 + ((((j >> 3) ^ (d & 7)) << 3) | (j & 7))] = val;
  }

  // S = q k^T  (K-dim = hd = 32: one MFMA per 16x16 tile)
  f32x4 s[4][4] = {};
  {
    bf16x8 kf[4];
#pragma unroll
    for (int nj = 0; nj < 4; ++nj)
      kf[nj] = *reinterpret_cast<const bf16x8*>(kg + (nj * 16 + l15) * 32 + l4 * 8);
#pragma unroll
    for (int mi = 0; mi < 4; ++mi) {
      const bf16x8 af = *reinterpret_cast<const bf16x8*>(qg + (mi * 16 + l15) * 32 + l4 * 8);
#pragma unroll
      for (int nj = 0; nj < 4; ++nj)
        s[mi][nj] = MFMA_BF16(af, kf[nj], s[mi][nj]);
    }
  }

  // masked softmax over j (cols >= 49 masked), all 64 lanes active.
  // Row i lives in the 16 lanes sharing l>>4; reduce with shfl_xor 1,2,4,8.
  const float scale = 0.17677669529663687f;  // 32^-0.5
#pragma unroll
  for (int mi = 0; mi < 4; ++mi) {
#pragma unroll
    for (int r = 0; r < 4; ++r) {
      float v[4]; float mx = -3.0e38f;
#pragma unroll
      for (int nj = 0; nj < 4; ++nj) {
        const int col = nj * 16 + l15;
        float sv = s[mi][nj][r] * scale;
        sv = (col < 49) ? sv : -3.0e38f;
        v[nj] = sv; mx = fmaxf(mx, sv);
      }
#pragma unroll
      for (int off = 1; off < 16; off <<= 1) mx = fmaxf(mx, __shfl_xor(mx, off));
      float e[4]; float sum = 0.f;
#pragma unroll
      for (int nj = 0; nj < 4; ++nj) { e[nj] = __expf(v[nj] - mx); sum += e[nj]; }
#pragma unroll
      for (int off = 1; off < 16; off <<= 1) sum += __shfl_xor(sum, off);
      const float inv = 1.0f / sum;
      const int row = mi * 16 + l4 * 4 + r;
#pragma unroll
      for (int nj = 0; nj < 4; ++nj) {
        const int col = nj * 16 + l15;
        Pl[row * 64 + ((((col >> 3) ^ (row & 7)) << 3) | (col & 7))] = f2bf(e[nj] * inv);
      }
    }
  }
  __syncthreads();

  // O = P V   (K-dim = 64 padded j; P cols >=49 are exactly 0, V rows >=49 are 0)
  f32x4 oa[4][2] = {};
#pragma unroll
  for (int ksj = 0; ksj < 2; ++ksj) {
    const int chunk = ksj * 4 + l4;
    bf16x8 vb[2];
#pragma unroll
    for (int dt = 0; dt < 2; ++dt) {
      const int d = dt * 16 + l15;
      vb[dt] = *reinterpret_cast<const bf16x8*>(&vT[d * 64 + ((chunk ^ (d & 7)) << 3)]);
    }
#pragma unroll
    for (int mi = 0; mi < 4; ++mi) {
      const int row = mi * 16 + l15;
      const bf16x8 pa = *reinterpret_cast<const bf16x8*>(&Pl[row * 64 + ((chunk ^ (row & 7)) << 3)]);
#pragma unroll
      for (int dt = 0; dt < 2; ++dt)
        oa[mi][dt] = MFMA_BF16(pa, vb[dt], oa[mi][dt]);
    }
  }

  // write O (rows i < 49) token-major bf16: o[token][h*32 + d]
  const int wy = win >> 4, wx = win & 15;
#pragma unroll
  for (int mi = 0; mi < 4; ++mi) {
#pragma unroll
    for (int r = 0; r < 4; ++r) {
      const int i = mi * 16 + l4 * 4 + r;
      if (i < 49) {
        const int ty = i / 7, tx = i - ty * 7;
        const size_t m = (size_t)b * 12544 + (size_t)(wy * 7 + ty) * 112 + (wx * 7 + tx);
#pragma unroll
        for (int dt = 0; dt < 2; ++dt)
          o[m * 256 + h * 32 + dt * 16 + l15] = f2bf(oa[mi][dt][r]);
      }
    }
  }
}

// ---------------------------------------------------------------------------
// Kernel 3: out = o @ proj_w^T + proj_b  (bf16 A, fp32 out). Same skeleton.
// ---------------------------------------------------------------------------
__global__ __launch_bounds__(256) void k_proj(const unsigned short* __restrict__ a,
                                              const float* __restrict__ w,
                                              const float* __restrict__ bias,
                                              float* __restrict__ out) {
  __shared__ unsigned short As[2][128 * LDA];
  __shared__ unsigned short Bs[2][128 * LDA];

  const int id = blockIdx.x;
  const int wg = (id & 7) * 196 + (id >> 3);   // 1568 = 8*196
  const int mt = wg >> 1, nt = wg & 1;
  const int m0 = mt * 128, n0 = nt * 128;

  const int tid = threadIdx.x;
  const int lane = tid & 63, wid = tid >> 6;
  const int wr = (wid >> 1) * 64, wc = (wid & 1) * 64;
  const int l15 = lane & 15, l4 = lane >> 4;

  const int arow = tid >> 2, akc = (tid & 3) * 8;  // bf16 A: 16B chunks
  const int brow = tid >> 3, bkc = (tid & 7) * 4;  // fp32 B: float4 chunks

  f32x4 acc[4][4] = {};
  uint4 ar[2]; float4 br[4];

#pragma unroll
  for (int p = 0; p < 2; ++p)
    ar[p] = *reinterpret_cast<const uint4*>(a + (size_t)(m0 + arow + p * 64) * 256 + akc);
#pragma unroll
  for (int p = 0; p < 4; ++p)
    br[p] = *reinterpret_cast<const float4*>(w + (size_t)(n0 + brow + p * 32) * 256 + bkc);
#pragma unroll
  for (int p = 0; p < 2; ++p)
    *reinterpret_cast<uint4*>(&As[0][(arow + p * 64) * LDA + akc]) = ar[p];
#pragma unroll
  for (int p = 0; p < 4; ++p) {
    union { unsigned short u[4]; uint2 v; } pb;
    pb.u[0] = f2bf(br[p].x); pb.u[1] = f2bf(br[p].y); pb.u[2] = f2bf(br[p].z); pb.u[3] = f2bf(br[p].w);
    *reinterpret_cast<uint2*>(&Bs[0][(brow + p * 32) * LDA + bkc]) = pb.v;
  }

  for (int ks = 0; ks < 8; ++ks) {
    __syncthreads();
    const int buf = ks & 1;
    if (ks < 7) {
      const int k0 = (ks + 1) * 32;
#pragma unroll
      for (int p = 0; p < 2; ++p)
        ar[p] = *reinterpret_cast<const uint4*>(a + (size_t)(m0 + arow + p * 64) * 256 + k0 + akc);
#pragma unroll
      for (int p = 0; p < 4; ++p)
        br[p] = *reinterpret_cast<const float4*>(w + (size_t)(n0 + brow + p * 32) * 256 + k0 + bkc);
    }
    bf16x8 af[4], bfr[4];
#pragma unroll
    for (int i = 0; i < 4; ++i) {
      af[i]  = *reinterpret_cast<const bf16x8*>(&As[buf][(wr + i * 16 + l15) * LDA + l4 * 8]);
      bfr[i] = *reinterpret_cast<const bf16x8*>(&Bs[buf][(wc + i * 16 + l15) * LDA + l4 * 8]);
    }
#pragma unroll
    for (int mi = 0; mi < 4; ++mi)
#pragma unroll
      for (int ni = 0; ni < 4; ++ni)
        acc[mi][ni] = MFMA_BF16(af[mi], bfr[ni], acc[mi][ni]);
    if (ks < 7) {
#pragma unroll
      for (int p = 0; p < 2; ++p)
        *reinterpret_cast<uint4*>(&As[buf ^ 1][(arow + p * 64) * LDA + akc]) = ar[p];
#pragma unroll
      for (int p = 0; p < 4; ++p) {
        union { unsigned short u[4]; uint2 v; } pb;
        pb.u[0] = f2bf(br[p].x); pb.u[1] = f2bf(br[p].y); pb.u[2] = f2bf(br[p].z); pb.u[3] = f2bf(br[p].w);
        *reinterpret_cast<uint2*>(&Bs[buf ^ 1][(brow + p * 32) * LDA + bkc]) = pb.v;
      }
    }
  }

  float bv[4];
#pragma unroll
  for (int ni = 0; ni < 4; ++ni) bv[ni] = bias[n0 + wc + ni * 16 + l15];
#pragma unroll
  for (int mi = 0; mi < 4; ++mi) {
#pragma unroll
    for (int r = 0; r < 4; ++r) {
      const int mrow = m0 + wr + mi * 16 + l4 * 4 + r;
      float* orow = out + (size_t)mrow * 256 + n0 + wc;
#pragma unroll
      for (int ni = 0; ni < 4; ++ni)
        orow[ni * 16 + l15] = acc[mi][ni][r] + bv[ni];
    }
  }
}

// ---------------------------------------------------------------------------
extern "C" void kernel_launch(void* const* d_in, const int* in_sizes, int n_in,
                              void* d_out, int out_size, void* d_ws, size_t ws_size,
                              hipStream_t stream) {
  (void)in_sizes; (void)n_in; (void)out_size; (void)ws_size;
  const float* x      = (const float*)d_in[0];
  const float* qkv_w  = (const float*)d_in[1];
  const float* qkv_b  = (const float*)d_in[2];
  const float* proj_w = (const float*)d_in[3];
  const float* proj_b = (const float*)d_in[4];
  // d_in[5]=H, d_in[6]=W are compile-time constants here (112, 112)

  unsigned short* qkv_ws = (unsigned short*)d_ws;                       // 77,070,336 bf16 = 154.1 MB
  unsigned short* o_ws   = (unsigned short*)((char*)d_ws + 154140672);  // 25,690,112 bf16 = 51.4 MB
  float* out = (float*)d_out;

  k_qkv<<<dim3(4704), dim3(256), 0, stream>>>(x, qkv_w, qkv_b, qkv_ws);
  k_attn<<<dim3(16384), dim3(64), 0, stream>>>(qkv_ws, o_ws);
  k_proj<<<dim3(1568), dim3(256), 0, stream>>>(o_ws, proj_w, proj_b, out);
}

// Round 2
// 446.823 us; speedup vs baseline: 1.0490x; 1.0490x over previous
//
#include <hip/hip_runtime.h>
#include <cstdint>
#include <cstddef>

// ---------------------------------------------------------------------------
// LocallyGroupedAttn fused pipeline, MI355X / gfx950
// B=8, H=W=112, C=256, ws=7, heads=8, hd=32 (no padding).
//   [k_wconv] qkv_w + proj_w fp32 -> bf16 table in ws      (1 MB traffic)
//   [k_fused] per-window block: x->bf16 LDS, qkv GEMM per (wave,head),
//             49x49 attention in wave-private LDS, write o bf16
//   [k_proj ] out = o @ proj_w^T + b   (both operands bf16, fp32 out)
// Kills the 154 MB qkv intermediate (+its re-read) from round 1.
// ---------------------------------------------------------------------------

typedef __attribute__((ext_vector_type(8))) short bf16x8;
typedef __attribute__((ext_vector_type(4))) float f32x4;

#define MFMA_BF16(a, b, c) __builtin_amdgcn_mfma_f32_16x16x32_bf16((a), (b), (c), 0, 0, 0)

__device__ __forceinline__ unsigned short f2bf(float f) {
  unsigned int u = __builtin_bit_cast(unsigned int, f);
  u += 0x7fffu + ((u >> 16) & 1u);          // round-to-nearest-even
  return (unsigned short)(u >> 16);
}
__device__ __forceinline__ unsigned int pack2(float a, float b) {
  return (unsigned int)f2bf(a) | ((unsigned int)f2bf(b) << 16);
}

// ---------------------------------------------------------------------------
// Kernel 0: convert qkv_w (196608 f32) and proj_w (65536 f32) to bf16.
// wb layout: [0..196607] = qkv_w rows, [196608..262143] = proj_w rows.
// ---------------------------------------------------------------------------
__global__ __launch_bounds__(256) void k_wconv(const float* __restrict__ qkv_w,
                                               const float* __restrict__ proj_w,
                                               unsigned short* __restrict__ wb) {
  const int gid = blockIdx.x * 256 + threadIdx.x;   // 65536 threads, 4 f32 each
  const float4 v = (gid < 49152)
      ? *reinterpret_cast<const float4*>(qkv_w + (size_t)gid * 4)
      : *reinterpret_cast<const float4*>(proj_w + (size_t)(gid - 49152) * 4);
  uint2 p; p.x = pack2(v.x, v.y); p.y = pack2(v.z, v.w);
  *reinterpret_cast<uint2*>(wb + (size_t)gid * 4) = p;
}

// ---------------------------------------------------------------------------
// Kernel 1: fused qkv projection + windowed attention.
// Grid 2048 = (b, win). Block 256 thr = 4 waves; wave w handles heads 2w,2w+1.
// LDS (80 KB exact -> 2 blocks/CU):
//   [0, 32768)      xs: 64 rows x 256 bf16, byte = row*512 + (cb ^ ((row&7)<<4))
//                   rows 49..63 never written (garbage; row-local, discarded)
//   [32768 + wid*12288): per-wave region:
//        q  [64][32] bf16 (4 KB)   \ aliased by Pl [64][64] XOR-swizzled (8 KB)
//        k  [64][32] bf16 (4 KB)   /
//        vT [32][64] bf16 XOR-swizzled (4 KB), rows j>=49 zeroed
// ---------------------------------------------------------------------------
__global__ __launch_bounds__(256, 2) void k_fused(const float* __restrict__ x,
                                                  const unsigned short* __restrict__ wb,
                                                  const float* __restrict__ qkv_b,
                                                  unsigned short* __restrict__ o) {
  __shared__ char lds_raw[81920];

  const int tid = threadIdx.x, lane = tid & 63, wid = tid >> 6;
  const int l15 = lane & 15, l4 = lane >> 4;
  const int bid = blockIdx.x;
  const int b = bid >> 8, win = bid & 255, wy = win >> 4, wx = win & 15;

  // ---- stage x window (49 rows x 256 f32 -> bf16, swizzled) ----
  const float* xw = x + ((size_t)(b * 112 + wy * 7) * 112 + wx * 7) * 256;
  for (int idx = tid; idx < 3136; idx += 256) {       // 49 rows * 64 chunks
    const int row = idx >> 6, kc = idx & 63;
    const int ty = row / 7, tx = row - ty * 7;
    const float4 v = *reinterpret_cast<const float4*>(xw + ((size_t)(ty * 112 + tx)) * 256 + kc * 4);
    uint2 p; p.x = pack2(v.x, v.y); p.y = pack2(v.z, v.w);
    *reinterpret_cast<uint2*>(lds_raw + row * 512 + ((kc * 8) ^ ((row & 7) << 4))) = p;
  }
  __syncthreads();   // the only block-wide barrier; everything after is wave-private

  unsigned short* qs  = (unsigned short*)(lds_raw + 32768 + wid * 12288); // [tok][32]
  unsigned short* ks_ = qs + 2048;                                        // [tok][32]
  unsigned short* vTs = qs + 4096;                                        // [d][64] swz
  unsigned short* Pls = qs;                                               // alias q+k

  for (int hh = 0; hh < 2; ++hh) {
    const int h = wid * 2 + hh;

    // ---- qkv GEMM for this head: acc[mi][ni], ni = {q0,q1,k0,k1,v0,v1} ----
    f32x4 acc[4][6] = {};
    const unsigned short* wrow[6];
    float bias[6];
#pragma unroll
    for (int ni = 0; ni < 6; ++ni) {
      const int col = (ni >> 1) * 256 + h * 32 + (ni & 1) * 16 + l15;
      wrow[ni] = wb + (size_t)col * 256 + l4 * 8;
      bias[ni] = qkv_b[col];
    }
    for (int ks = 0; ks < 8; ++ks) {
      bf16x8 af[4], bf[6];
#pragma unroll
      for (int mi = 0; mi < 4; ++mi) {
        const int row = mi * 16 + l15;
        af[mi] = *reinterpret_cast<const bf16x8*>(
            lds_raw + row * 512 + ((ks * 64 + l4 * 16) ^ ((row & 7) << 4)));
      }
#pragma unroll
      for (int ni = 0; ni < 6; ++ni)
        bf[ni] = *reinterpret_cast<const bf16x8*>(wrow[ni] + ks * 32);
#pragma unroll
      for (int mi = 0; mi < 4; ++mi)
#pragma unroll
        for (int ni = 0; ni < 6; ++ni)
          acc[mi][ni] = MFMA_BF16(af[mi], bf[ni], acc[mi][ni]);
    }

    // ---- write q,k (scalar) and vT (packed, swizzled, zero tok>=49) ----
    asm volatile("" ::: "memory");   // order after previous head's PV reads
#pragma unroll
    for (int mi = 0; mi < 4; ++mi) {
      const int tokb = mi * 16 + l4 * 4;
#pragma unroll
      for (int r = 0; r < 4; ++r) {
#pragma unroll
        for (int ni = 0; ni < 4; ++ni) {
          const float val = acc[mi][ni][r] + bias[ni];
          const int d = (ni & 1) * 16 + l15;
          ((ni < 2) ? qs : ks_)[(tokb + r) * 32 + d] = f2bf(val);
        }
      }
#pragma unroll
      for (int ni = 4; ni < 6; ++ni) {
        const int d = (ni - 4) * 16 + l15;
        float v0 = acc[mi][ni][0] + bias[ni], v1 = acc[mi][ni][1] + bias[ni];
        float v2 = acc[mi][ni][2] + bias[ni], v3 = acc[mi][ni][3] + bias[ni];
        if (tokb + 0 >= 49) v0 = 0.f;
        if (tokb + 1 >= 49) v1 = 0.f;
        if (tokb + 2 >= 49) v2 = 0.f;
        if (tokb + 3 >= 49) v3 = 0.f;
        // vT elem index: d*64 + ((((j>>3)^(d&7))<<3) | (j&7)); j = tokb+r
        const int ebase = d * 64 + ((((mi * 2 + (l4 >> 1)) ^ (d & 7)) << 3) | ((l4 & 1) * 4));
        uint2 p; p.x = pack2(v0, v1); p.y = pack2(v2, v3);
        *reinterpret_cast<uint2*>(vTs + ebase) = p;
      }
    }
    asm volatile("s_waitcnt lgkmcnt(0)" ::: "memory");
    __builtin_amdgcn_sched_barrier(0);

    // ---- S = q k^T (K = hd = 32, one MFMA per 16x16 tile) ----
    f32x4 s[4][4] = {};
    {
      bf16x8 kf[4];
#pragma unroll
      for (int nj = 0; nj < 4; ++nj)
        kf[nj] = *reinterpret_cast<const bf16x8*>(ks_ + (nj * 16 + l15) * 32 + l4 * 8);
#pragma unroll
      for (int mi = 0; mi < 4; ++mi) {
        const bf16x8 qf = *reinterpret_cast<const bf16x8*>(qs + (mi * 16 + l15) * 32 + l4 * 8);
#pragma unroll
        for (int nj = 0; nj < 4; ++nj)
          s[mi][nj] = MFMA_BF16(qf, kf[nj], s[mi][nj]);
      }
    }

    // ---- masked wave-parallel softmax (verbatim round-1, verified) ----
    const float scale = 0.17677669529663687f;  // 32^-0.5
#pragma unroll
    for (int mi = 0; mi < 4; ++mi) {
#pragma unroll
      for (int r = 0; r < 4; ++r) {
        float v[4]; float mx = -3.0e38f;
#pragma unroll
        for (int nj = 0; nj < 4; ++nj) {
          const int col = nj * 16 + l15;
          float sv = s[mi][nj][r] * scale;
          sv = (col < 49) ? sv : -3.0e38f;
          v[nj] = sv; mx = fmaxf(mx, sv);
        }
#pragma unroll
        for (int off = 1; off < 16; off <<= 1) mx = fmaxf(mx, __shfl_xor(mx, off));
        float e[4]; float sum = 0.f;
#pragma unroll
        for (int nj = 0; nj < 4; ++nj) { e[nj] = __expf(v[nj] - mx); sum += e[nj]; }
#pragma unroll
        for (int off = 1; off < 16; off <<= 1) sum += __shfl_xor(sum, off);
        const float inv = 1.0f / sum;
        const int row = mi * 16 + l4 * 4 + r;
#pragma unroll
        for (int nj = 0; nj < 4; ++nj) {
          const int col = nj * 16 + l15;
          Pls[row * 64 + ((((col >> 3) ^ (row & 7)) << 3) | (col & 7))] = f2bf(e[nj] * inv);
        }
      }
    }
    asm volatile("s_waitcnt lgkmcnt(0)" ::: "memory");
    __builtin_amdgcn_sched_barrier(0);

    // ---- O = P V (K = 64 padded; P cols>=49 are 0, vT rows>=49 are 0) ----
    f32x4 oa[4][2] = {};
#pragma unroll
    for (int ksj = 0; ksj < 2; ++ksj) {
      const int chunk = ksj * 4 + l4;
      bf16x8 vb[2];
#pragma unroll
      for (int dt = 0; dt < 2; ++dt) {
        const int d = dt * 16 + l15;
        vb[dt] = *reinterpret_cast<const bf16x8*>(vTs + d * 64 + ((chunk ^ (d & 7)) << 3));
      }
#pragma unroll
      for (int mi = 0; mi < 4; ++mi) {
        const int row = mi * 16 + l15;
        const bf16x8 pa = *reinterpret_cast<const bf16x8*>(Pls + row * 64 + ((chunk ^ (row & 7)) << 3));
#pragma unroll
        for (int dt = 0; dt < 2; ++dt)
          oa[mi][dt] = MFMA_BF16(pa, vb[dt], oa[mi][dt]);
      }
    }

    // ---- write O rows < 49, token-major bf16 ----
#pragma unroll
    for (int mi = 0; mi < 4; ++mi) {
#pragma unroll
      for (int r = 0; r < 4; ++r) {
        const int i = mi * 16 + l4 * 4 + r;
        if (i < 49) {
          const int ty = i / 7, tx = i - ty * 7;
          const size_t m = (size_t)b * 12544 + (size_t)(wy * 7 + ty) * 112 + (wx * 7 + tx);
#pragma unroll
          for (int dt = 0; dt < 2; ++dt)
            o[m * 256 + h * 32 + dt * 16 + l15] = f2bf(oa[mi][dt][r]);
        }
      }
    }
    asm volatile("" ::: "memory");   // keep next head's LDS writes after PV reads
  }
}

// ---------------------------------------------------------------------------
// Kernel 2: out = o @ proj_w^T + proj_b. Both operands bf16 -> staging is a
// pure uint4 copy (no conversion VALU). Tiles 128x128, BK=32, 4 waves.
// ---------------------------------------------------------------------------
__global__ __launch_bounds__(256) void k_proj(const unsigned short* __restrict__ a,
                                              const unsigned short* __restrict__ wbp,
                                              const float* __restrict__ bias,
                                              float* __restrict__ out) {
  __shared__ unsigned short As[2][128 * 32];
  __shared__ unsigned short Bs[2][128 * 32];

  const int id = blockIdx.x;
  const int wg = (id & 7) * 196 + (id >> 3);   // 1568 = 8*196, bijective
  const int mt = wg >> 1, nt = wg & 1;
  const int m0 = mt * 128, n0 = nt * 128;

  const int tid = threadIdx.x, lane = tid & 63, wid = tid >> 6;
  const int wr = (wid >> 1) * 64, wc = (wid & 1) * 64;
  const int l15 = lane & 15, l4 = lane >> 4;

  const int srow = tid >> 2;          // 0..63 (+64 second pass)
  const int ske  = (tid & 3) * 8;     // bf16 elem offset within BK=32 row

  f32x4 acc[4][4] = {};
  uint4 ar[2], br[2];

#pragma unroll
  for (int p = 0; p < 2; ++p) {
    ar[p] = *reinterpret_cast<const uint4*>(a   + (size_t)(m0 + srow + p * 64) * 256 + ske);
    br[p] = *reinterpret_cast<const uint4*>(wbp + (size_t)(n0 + srow + p * 64) * 256 + ske);
  }
#pragma unroll
  for (int p = 0; p < 2; ++p) {
    *reinterpret_cast<uint4*>(&As[0][(srow + p * 64) * 32 + ske]) = ar[p];
    *reinterpret_cast<uint4*>(&Bs[0][(srow + p * 64) * 32 + ske]) = br[p];
  }

  for (int ks = 0; ks < 8; ++ks) {
    __syncthreads();
    const int buf = ks & 1;
    if (ks < 7) {   // T14: issue next-tile loads before compute
      const int k0 = (ks + 1) * 32;
#pragma unroll
      for (int p = 0; p < 2; ++p) {
        ar[p] = *reinterpret_cast<const uint4*>(a   + (size_t)(m0 + srow + p * 64) * 256 + k0 + ske);
        br[p] = *reinterpret_cast<const uint4*>(wbp + (size_t)(n0 + srow + p * 64) * 256 + k0 + ske);
      }
    }
    bf16x8 af[4], bfr[4];
#pragma unroll
    for (int i = 0; i < 4; ++i) {
      af[i]  = *reinterpret_cast<const bf16x8*>(&As[buf][(wr + i * 16 + l15) * 32 + l4 * 8]);
      bfr[i] = *reinterpret_cast<const bf16x8*>(&Bs[buf][(wc + i * 16 + l15) * 32 + l4 * 8]);
    }
#pragma unroll
    for (int mi = 0; mi < 4; ++mi)
#pragma unroll
      for (int ni = 0; ni < 4; ++ni)
        acc[mi][ni] = MFMA_BF16(af[mi], bfr[ni], acc[mi][ni]);
    if (ks < 7) {   // write-late into the other buffer
#pragma unroll
      for (int p = 0; p < 2; ++p) {
        *reinterpret_cast<uint4*>(&As[buf ^ 1][(srow + p * 64) * 32 + ske]) = ar[p];
        *reinterpret_cast<uint4*>(&Bs[buf ^ 1][(srow + p * 64) * 32 + ske]) = br[p];
      }
    }
  }

  float bv[4];
#pragma unroll
  for (int ni = 0; ni < 4; ++ni) bv[ni] = bias[n0 + wc + ni * 16 + l15];
#pragma unroll
  for (int mi = 0; mi < 4; ++mi) {
#pragma unroll
    for (int r = 0; r < 4; ++r) {
      const int mrow = m0 + wr + mi * 16 + l4 * 4 + r;
      float* orow = out + (size_t)mrow * 256 + n0 + wc;
#pragma unroll
      for (int ni = 0; ni < 4; ++ni)
        orow[ni * 16 + l15] = acc[mi][ni][r] + bv[ni];
    }
  }
}

// ---------------------------------------------------------------------------
extern "C" void kernel_launch(void* const* d_in, const int* in_sizes, int n_in,
                              void* d_out, int out_size, void* d_ws, size_t ws_size,
                              hipStream_t stream) {
  (void)in_sizes; (void)n_in; (void)out_size; (void)ws_size;
  const float* x      = (const float*)d_in[0];
  const float* qkv_w  = (const float*)d_in[1];
  const float* qkv_b  = (const float*)d_in[2];
  const float* proj_w = (const float*)d_in[3];
  const float* proj_b = (const float*)d_in[4];

  unsigned short* wb_qkv  = (unsigned short*)d_ws;                      // 393216 B
  unsigned short* wb_proj = wb_qkv + 196608;                            // 131072 B
  unsigned short* o_ws    = (unsigned short*)((char*)d_ws + 524288);    // 51.4 MB
  float* out = (float*)d_out;

  k_wconv<<<dim3(256),  dim3(256), 0, stream>>>(qkv_w, proj_w, wb_qkv);
  k_fused<<<dim3(2048), dim3(256), 0, stream>>>(x, wb_qkv, qkv_b, o_ws);
  k_proj <<<dim3(1568), dim3(256), 0, stream>>>(o_ws, wb_proj, proj_b, out);
}

// Round 4
// 384.669 us; speedup vs baseline: 1.2185x; 1.1616x over previous
//
#include <hip/hip_runtime.h>
#include <cstdint>
#include <cstddef>

// ---------------------------------------------------------------------------
// LocallyGroupedAttn, MI355X / gfx950. B=8, H=W=112, C=256, ws=7, nh=8, hd=32.
// Pipeline:
//   [k_conv] x f32 -> bf16 (stream, once)
//   [k_qkv ] qkv = x@qkv_w^T+b  (A via global_load_lds DMA, B reg-converted),
//            LDS-transpose epilogue -> window-gathered bf16 [bw][3][h][49][32]
//   [k_attn] per (window,head) 49x49 attention (round-1 verified core),
//            O through LDS -> wide stores, o bf16 [token][256] (aliases x_bf)
//   [k_proj] out = o@proj_w^T+b (A via DMA, B reg-converted), f32 out
// ---------------------------------------------------------------------------

typedef __attribute__((ext_vector_type(8))) short bf16x8;
typedef __attribute__((ext_vector_type(4))) float f32x4;

#define MFMA_BF16(a, b, c) __builtin_amdgcn_mfma_f32_16x16x32_bf16((a), (b), (c), 0, 0, 0)

__device__ __forceinline__ unsigned short f2bf(float f) {
  unsigned int u = __builtin_bit_cast(unsigned int, f);
  u += 0x7fffu + ((u >> 16) & 1u);  // RNE
  return (unsigned short)(u >> 16);
}
__device__ __forceinline__ unsigned int pack2(float a, float b) {
  return (unsigned int)f2bf(a) | ((unsigned int)f2bf(b) << 16);
}
__device__ __forceinline__ void gl16(const unsigned short* g, unsigned short* l) {
  __builtin_amdgcn_global_load_lds(
      (const __attribute__((address_space(1))) unsigned int*)g,
      (__attribute__((address_space(3))) unsigned int*)l, 16, 0, 0);
}

// ---------------------------------------------------------------------------
// Kernel 0: x f32 -> bf16, 25,690,112 elems. 8 f32/thread, grid-stride.
// ---------------------------------------------------------------------------
__global__ __launch_bounds__(256) void k_conv(const float* __restrict__ x,
                                              unsigned short* __restrict__ xb) {
  const int NU = 3211264;  // 25690112 / 8
  for (int u = blockIdx.x * 256 + threadIdx.x; u < NU; u += 2048 * 256) {
    const float4 a = *reinterpret_cast<const float4*>(x + (size_t)u * 8);
    const float4 b = *reinterpret_cast<const float4*>(x + (size_t)u * 8 + 4);
    uint4 p;
    p.x = pack2(a.x, a.y); p.y = pack2(a.z, a.w);
    p.z = pack2(b.x, b.y); p.w = pack2(b.z, b.w);
    *reinterpret_cast<uint4*>(xb + (size_t)u * 8) = p;
  }
}

// ---------------------------------------------------------------------------
// Kernel 1: qkv GEMM. M=100352, N=768, K=256. BM=BN=128, BK=32, 4 waves.
// A staged via global_load_lds (bf16, no VALU); B (tiny, L2-hot) reg-converted.
// Epilogue: C -> LDS [128][136] bf16 -> 16B stores into gathered layout.
// ---------------------------------------------------------------------------
__global__ __launch_bounds__(256, 4) void k_qkv(const unsigned short* __restrict__ xb,
                                                const float* __restrict__ w,
                                                const float* __restrict__ bias,
                                                unsigned short* __restrict__ qkv) {
  __shared__ __align__(16) char lds[34816];  // A dbuf 16K | B dbuf 16K ; C-stage 34816
  unsigned short* As = (unsigned short*)lds;            // 2 x 4096 elems
  unsigned short* Bs = (unsigned short*)(lds + 16384);  // 2 x 4096 elems

  const int id = blockIdx.x;
  const int wg = (id & 7) * 588 + (id >> 3);  // 4704 = 8*588 bijective XCD swizzle
  const int mt = wg / 6, nt = wg - mt * 6;    // nt fastest -> A-panel L2 reuse
  const int m0 = mt * 128, n0 = nt * 128;

  const int t = threadIdx.x, lane = t & 63, wid = t >> 6;
  const int wr = (wid >> 1) * 64, wc = (wid & 1) * 64;
  const int l15 = lane & 15, l4 = lane >> 4;

  const int rA = t >> 2, cA = (t & 3) * 8;    // A DMA: 16B chunks, linear LDS
  const int rB = t >> 1, khB = (t & 1) * 16;  // B stage: row, k-half

  const unsigned short* gA0 = xb + (size_t)(m0 + rA) * 256 + cA;
  const unsigned short* gA1 = xb + (size_t)(m0 + 64 + rA) * 256 + cA;
  const float* gB = w + (size_t)(n0 + rB) * 256 + khB;

  f32x4 acc[4][4] = {};

  // prologue: tile 0 -> buf 0
  gl16(gA0, As + t * 8);
  gl16(gA1, As + 2048 + t * 8);
  {
    float4 b0 = *reinterpret_cast<const float4*>(gB);
    float4 b1 = *reinterpret_cast<const float4*>(gB + 4);
    uint4 p; p.x = pack2(b0.x, b0.y); p.y = pack2(b0.z, b0.w);
    p.z = pack2(b1.x, b1.y); p.w = pack2(b1.z, b1.w);
    *reinterpret_cast<uint4*>(Bs + rB * 32 + khB) = p;
    float4 b2 = *reinterpret_cast<const float4*>(gB + 8);
    float4 b3 = *reinterpret_cast<const float4*>(gB + 12);
    uint4 q; q.x = pack2(b2.x, b2.y); q.y = pack2(b2.z, b2.w);
    q.z = pack2(b3.x, b3.y); q.w = pack2(b3.z, b3.w);
    *reinterpret_cast<uint4*>(Bs + rB * 32 + khB + 8) = q;
  }
  __syncthreads();

  for (int ks = 0; ks < 8; ++ks) {
    const int cur = ks & 1;
    float4 b0, b1, b2, b3;
    if (ks < 7) {  // issue next-tile A DMA + B loads early (overlap with MFMA)
      const int k0 = (ks + 1) * 32;
      gl16(gA0 + k0, As + (cur ^ 1) * 4096 + t * 8);
      gl16(gA1 + k0, As + (cur ^ 1) * 4096 + 2048 + t * 8);
      b0 = *reinterpret_cast<const float4*>(gB + k0);
      b1 = *reinterpret_cast<const float4*>(gB + k0 + 4);
      b2 = *reinterpret_cast<const float4*>(gB + k0 + 8);
      b3 = *reinterpret_cast<const float4*>(gB + k0 + 12);
    }
    const unsigned short* Ab = As + cur * 4096;
    const unsigned short* Bb = Bs + cur * 4096;
    bf16x8 af[4], bfr[4];
#pragma unroll
    for (int i = 0; i < 4; ++i) {
      af[i]  = *reinterpret_cast<const bf16x8*>(Ab + (wr + i * 16 + l15) * 32 + l4 * 8);
      bfr[i] = *reinterpret_cast<const bf16x8*>(Bb + (wc + i * 16 + l15) * 32 + l4 * 8);
    }
#pragma unroll
    for (int mi = 0; mi < 4; ++mi)
#pragma unroll
      for (int ni = 0; ni < 4; ++ni)
        acc[mi][ni] = MFMA_BF16(af[mi], bfr[ni], acc[mi][ni]);
    if (ks < 7) {  // write-late B into other buffer
      unsigned short* Bn = Bs + (cur ^ 1) * 4096;
      uint4 p; p.x = pack2(b0.x, b0.y); p.y = pack2(b0.z, b0.w);
      p.z = pack2(b1.x, b1.y); p.w = pack2(b1.z, b1.w);
      *reinterpret_cast<uint4*>(Bn + rB * 32 + khB) = p;
      uint4 q; q.x = pack2(b2.x, b2.y); q.y = pack2(b2.z, b2.w);
      q.z = pack2(b3.x, b3.y); q.w = pack2(b3.z, b3.w);
      *reinterpret_cast<uint4*>(Bn + rB * 32 + khB + 8) = q;
    }
    __syncthreads();
  }

  // epilogue: +bias, bf16 -> LDS [128][136], then 16B stores to gathered layout
  float bv[4];
#pragma unroll
  for (int ni = 0; ni < 4; ++ni) bv[ni] = bias[n0 + wc + ni * 16 + l15];
  unsigned short* Cst = (unsigned short*)lds;
#pragma unroll
  for (int mi = 0; mi < 4; ++mi)
#pragma unroll
    for (int ni = 0; ni < 4; ++ni)
#pragma unroll
      for (int r = 0; r < 4; ++r)
        Cst[(wr + mi * 16 + l4 * 4 + r) * 136 + wc + ni * 16 + l15] =
            f2bf(acc[mi][ni][r] + bv[ni]);
  __syncthreads();

  const int which = n0 >> 8;        // 0=q,1=k,2=v
  const int hbase = (n0 >> 5) & 7;  // 0 or 4
#pragma unroll
  for (int p = 0; p < 2; ++p) {
    const int pair = p * 256 + t;   // 512 (token, head) pairs
    const int token = pair & 127, hidx = pair >> 7;
    const int mrow = m0 + token;
    const int b = mrow / 12544, pix = mrow - b * 12544;
    const int py = pix / 112, px = pix - py * 112;
    const int wy = py / 7, ty = py - wy * 7;
    const int wxx = px / 7, tx = px - wxx * 7;
    const int win = wy * 16 + wxx, tloc = ty * 7 + tx;
    const unsigned short* src = Cst + token * 136 + hidx * 32;
    unsigned short* dst = qkv +
        (((size_t)(b * 256 + win) * 3 + which) * 8 + hbase + hidx) * 1568 + tloc * 32;
#pragma unroll
    for (int c = 0; c < 4; ++c)
      *reinterpret_cast<uint4*>(dst + c * 8) = *reinterpret_cast<const uint4*>(src + c * 8);
  }
}

// ---------------------------------------------------------------------------
// Kernel 2: per (window, head) attention. 1 wave/block, 16384 blocks.
// Round-1 verified core; vectorized V staging; O through LDS -> 16B stores.
// ---------------------------------------------------------------------------
__global__ __launch_bounds__(64) void k_attn(const unsigned short* __restrict__ qkv,
                                             unsigned short* __restrict__ o) {
  __shared__ unsigned short vT[32 * 64];  // [d][j] XOR-swizzled, rows j>=49 zeroed
  __shared__ unsigned short Pl[64 * 64];  // [i][j] XOR-swizzled; later aliased by Ost

  const int lane = threadIdx.x;
  const int l15 = lane & 15, l4 = lane >> 4;

  const int bid = blockIdx.x;
  const int h = bid & 7;
  const int bw = bid >> 3;
  const int b = bw >> 8, win = bw & 255;

  const unsigned short* qg = qkv + ((size_t)bw * 24 + h) * 1568;
  const unsigned short* kg = qkv + ((size_t)bw * 24 + 8 + h) * 1568;
  const unsigned short* vg = qkv + ((size_t)bw * 24 + 16 + h) * 1568;

  // stage V transposed+swizzled, vectorized reads (uint4 = 8 bf16)
#pragma unroll
  for (int it = 0; it < 4; ++it) {
    const int j = it * 16 + (lane >> 2), d0 = (lane & 3) * 8;
    uint4 vv = {0, 0, 0, 0};
    if (j < 49) vv = *reinterpret_cast<const uint4*>(vg + j * 32 + d0);
    union { uint4 v; unsigned short u[8]; } un; un.v = vv;
#pragma unroll
    for (int e = 0; e < 8; ++e) {
      const int d = d0 + e;
      vT[d * 64 + ((((j >> 3) ^ (d & 7)) << 3) | (j & 7))] = un.u[e];
    }
  }

  // S = q k^T (K = hd = 32)
  f32x4 s[4][4] = {};
  {
    bf16x8 kf[4];
#pragma unroll
    for (int nj = 0; nj < 4; ++nj)
      kf[nj] = *reinterpret_cast<const bf16x8*>(kg + (nj * 16 + l15) * 32 + l4 * 8);
#pragma unroll
    for (int mi = 0; mi < 4; ++mi) {
      const bf16x8 qf = *reinterpret_cast<const bf16x8*>(qg + (mi * 16 + l15) * 32 + l4 * 8);
#pragma unroll
      for (int nj = 0; nj < 4; ++nj)
        s[mi][nj] = MFMA_BF16(qf, kf[nj], s[mi][nj]);
    }
  }

  // masked wave-parallel softmax (verified)
  const float scale = 0.17677669529663687f;
#pragma unroll
  for (int mi = 0; mi < 4; ++mi) {
#pragma unroll
    for (int r = 0; r < 4; ++r) {
      float v[4]; float mx = -3.0e38f;
#pragma unroll
      for (int nj = 0; nj < 4; ++nj) {
        const int col = nj * 16 + l15;
        float sv = s[mi][nj][r] * scale;
        sv = (col < 49) ? sv : -3.0e38f;
        v[nj] = sv; mx = fmaxf(mx, sv);
      }
#pragma unroll
      for (int off = 1; off < 16; off <<= 1) mx = fmaxf(mx, __shfl_xor(mx, off));
      float e[4]; float sum = 0.f;
#pragma unroll
      for (int nj = 0; nj < 4; ++nj) { e[nj] = __expf(v[nj] - mx); sum += e[nj]; }
#pragma unroll
      for (int off = 1; off < 16; off <<= 1) sum += __shfl_xor(sum, off);
      const float inv = 1.0f / sum;
      const int row = mi * 16 + l4 * 4 + r;
#pragma unroll
      for (int nj = 0; nj < 4; ++nj) {
        const int col = nj * 16 + l15;
        Pl[row * 64 + ((((col >> 3) ^ (row & 7)) << 3) | (col & 7))] = f2bf(e[nj] * inv);
      }
    }
  }

  // O = P V (K = 64 padded; vT rows >= 49 are zero)
  f32x4 oa[4][2] = {};
#pragma unroll
  for (int ksj = 0; ksj < 2; ++ksj) {
    const int chunk = ksj * 4 + l4;
    bf16x8 vb[2];
#pragma unroll
    for (int dt = 0; dt < 2; ++dt) {
      const int d = dt * 16 + l15;
      vb[dt] = *reinterpret_cast<const bf16x8*>(&vT[d * 64 + ((chunk ^ (d & 7)) << 3)]);
    }
#pragma unroll
    for (int mi = 0; mi < 4; ++mi) {
      const int row = mi * 16 + l15;
      const bf16x8 pa = *reinterpret_cast<const bf16x8*>(&Pl[row * 64 + ((chunk ^ (row & 7)) << 3)]);
#pragma unroll
      for (int dt = 0; dt < 2; ++dt)
        oa[mi][dt] = MFMA_BF16(pa, vb[dt], oa[mi][dt]);
    }
  }

  // O -> LDS [64][40] (aliases Pl; fence: all pa/vb ds_reads landed first)
  asm volatile("s_waitcnt lgkmcnt(0)" ::: "memory");
  __builtin_amdgcn_sched_barrier(0);
  unsigned short* Ost = Pl;
#pragma unroll
  for (int mi = 0; mi < 4; ++mi)
#pragma unroll
    for (int r = 0; r < 4; ++r) {
      const int i = mi * 16 + l4 * 4 + r;
#pragma unroll
      for (int dt = 0; dt < 2; ++dt)
        Ost[i * 40 + dt * 16 + l15] = f2bf(oa[mi][dt][r]);
    }

  // wide 16B stores, token-major o[token][256]
  const int wy = win >> 4, wx = win & 15;
  if (lane < 49) {
    const int ty = lane / 7, tx = lane - ty * 7;
    const size_t m = (size_t)b * 12544 + (size_t)(wy * 7 + ty) * 112 + (wx * 7 + tx);
    unsigned short* dst = o + m * 256 + h * 32;
#pragma unroll
    for (int c = 0; c < 4; ++c)
      *reinterpret_cast<uint4*>(dst + c * 8) =
          *reinterpret_cast<const uint4*>(Ost + lane * 40 + c * 8);
  }
}

// ---------------------------------------------------------------------------
// Kernel 3: out = o @ proj_w^T + proj_b. M=100352, N=256, K=256. Same GEMM
// skeleton as k_qkv (A DMA, B reg-converted); f32 epilogue stores.
// ---------------------------------------------------------------------------
__global__ __launch_bounds__(256, 4) void k_proj(const unsigned short* __restrict__ a,
                                                 const float* __restrict__ w,
                                                 const float* __restrict__ bias,
                                                 float* __restrict__ out) {
  __shared__ __align__(16) char lds[32768];
  unsigned short* As = (unsigned short*)lds;
  unsigned short* Bs = (unsigned short*)(lds + 16384);

  const int id = blockIdx.x;
  const int wg = (id & 7) * 196 + (id >> 3);  // 1568 = 8*196
  const int mt = wg >> 1, nt = wg & 1;
  const int m0 = mt * 128, n0 = nt * 128;

  const int t = threadIdx.x, lane = t & 63, wid = t >> 6;
  const int wr = (wid >> 1) * 64, wc = (wid & 1) * 64;
  const int l15 = lane & 15, l4 = lane >> 4;

  const int rA = t >> 2, cA = (t & 3) * 8;
  const int rB = t >> 1, khB = (t & 1) * 16;

  const unsigned short* gA0 = a + (size_t)(m0 + rA) * 256 + cA;
  const unsigned short* gA1 = a + (size_t)(m0 + 64 + rA) * 256 + cA;
  const float* gB = w + (size_t)(n0 + rB) * 256 + khB;

  f32x4 acc[4][4] = {};

  gl16(gA0, As + t * 8);
  gl16(gA1, As + 2048 + t * 8);
  {
    float4 b0 = *reinterpret_cast<const float4*>(gB);
    float4 b1 = *reinterpret_cast<const float4*>(gB + 4);
    uint4 p; p.x = pack2(b0.x, b0.y); p.y = pack2(b0.z, b0.w);
    p.z = pack2(b1.x, b1.y); p.w = pack2(b1.z, b1.w);
    *reinterpret_cast<uint4*>(Bs + rB * 32 + khB) = p;
    float4 b2 = *reinterpret_cast<const float4*>(gB + 8);
    float4 b3 = *reinterpret_cast<const float4*>(gB + 12);
    uint4 q; q.x = pack2(b2.x, b2.y); q.y = pack2(b2.z, b2.w);
    q.z = pack2(b3.x, b3.y); q.w = pack2(b3.z, b3.w);
    *reinterpret_cast<uint4*>(Bs + rB * 32 + khB + 8) = q;
  }
  __syncthreads();

  for (int ks = 0; ks < 8; ++ks) {
    const int cur = ks & 1;
    float4 b0, b1, b2, b3;
    if (ks < 7) {
      const int k0 = (ks + 1) * 32;
      gl16(gA0 + k0, As + (cur ^ 1) * 4096 + t * 8);
      gl16(gA1 + k0, As + (cur ^ 1) * 4096 + 2048 + t * 8);
      b0 = *reinterpret_cast<const float4*>(gB + k0);
      b1 = *reinterpret_cast<const float4*>(gB + k0 + 4);
      b2 = *reinterpret_cast<const float4*>(gB + k0 + 8);
      b3 = *reinterpret_cast<const float4*>(gB + k0 + 12);
    }
    const unsigned short* Ab = As + cur * 4096;
    const unsigned short* Bb = Bs + cur * 4096;
    bf16x8 af[4], bfr[4];
#pragma unroll
    for (int i = 0; i < 4; ++i) {
      af[i]  = *reinterpret_cast<const bf16x8*>(Ab + (wr + i * 16 + l15) * 32 + l4 * 8);
      bfr[i] = *reinterpret_cast<const bf16x8*>(Bb + (wc + i * 16 + l15) * 32 + l4 * 8);
    }
#pragma unroll
    for (int mi = 0; mi < 4; ++mi)
#pragma unroll
      for (int ni = 0; ni < 4; ++ni)
        acc[mi][ni] = MFMA_BF16(af[mi], bfr[ni], acc[mi][ni]);
    if (ks < 7) {
      unsigned short* Bn = Bs + (cur ^ 1) * 4096;
      uint4 p; p.x = pack2(b0.x, b0.y); p.y = pack2(b0.z, b0.w);
      p.z = pack2(b1.x, b1.y); p.w = pack2(b1.z, b1.w);
      *reinterpret_cast<uint4*>(Bn + rB * 32 + khB) = p;
      uint4 q; q.x = pack2(b2.x, b2.y); q.y = pack2(b2.z, b2.w);
      q.z = pack2(b3.x, b3.y); q.w = pack2(b3.z, b3.w);
      *reinterpret_cast<uint4*>(Bn + rB * 32 + khB + 8) = q;
    }
    __syncthreads();
  }

  float bv[4];
#pragma unroll
  for (int ni = 0; ni < 4; ++ni) bv[ni] = bias[n0 + wc + ni * 16 + l15];
#pragma unroll
  for (int mi = 0; mi < 4; ++mi)
#pragma unroll
    for (int r = 0; r < 4; ++r) {
      const int mrow = m0 + wr + mi * 16 + l4 * 4 + r;
      float* orow = out + (size_t)mrow * 256 + n0 + wc;
#pragma unroll
      for (int ni = 0; ni < 4; ++ni)
        orow[ni * 16 + l15] = acc[mi][ni][r] + bv[ni];
    }
}

// ---------------------------------------------------------------------------
extern "C" void kernel_launch(void* const* d_in, const int* in_sizes, int n_in,
                              void* d_out, int out_size, void* d_ws, size_t ws_size,
                              hipStream_t stream) {
  (void)in_sizes; (void)n_in; (void)out_size; (void)ws_size;
  const float* x      = (const float*)d_in[0];
  const float* qkv_w  = (const float*)d_in[1];
  const float* qkv_b  = (const float*)d_in[2];
  const float* proj_w = (const float*)d_in[3];
  const float* proj_b = (const float*)d_in[4];

  unsigned short* wsb  = (unsigned short*)d_ws;
  unsigned short* xb   = wsb;             // 25,690,112 bf16 (51.38 MB)
  unsigned short* qkvg = wsb + 25690112;  // 77,070,336 bf16 (154.14 MB)
  unsigned short* ob   = xb;              // o aliases x_bf (dead after k_qkv)
  float* out = (float*)d_out;             // total ws use = 205,520,896 B (proven)

  k_conv<<<dim3(2048),  dim3(256), 0, stream>>>(x, xb);
  k_qkv <<<dim3(4704),  dim3(256), 0, stream>>>(xb, qkv_w, qkv_b, qkvg);
  k_attn<<<dim3(16384), dim3(64),  0, stream>>>(qkvg, ob);
  k_proj<<<dim3(1568),  dim3(256), 0, stream>>>(ob, proj_w, proj_b, out);
}

// Round 5
// 357.756 us; speedup vs baseline: 1.3102x; 1.0752x over previous
//
#include <hip/hip_runtime.h>
#include <cstdint>
#include <cstddef>

// ---------------------------------------------------------------------------
// LocallyGroupedAttn, MI355X / gfx950. B=8, H=W=112, C=256, ws=7, nh=8, hd=32.
//   [k_conv] x f32 -> bf16; qkv_w/proj_w f32 -> bf16 table (ws tail)
//   [k_qkv ] qkv GEMM, A+B via global_load_lds DMA w/ pre-swizzled sources,
//            counted-vmcnt 2-barrier pipeline; gather epilogue
//   [k_attn] per (window,head) 49x49 attention (verified, unchanged)
//   [k_proj] proj GEMM, same structure, f32 out
// ---------------------------------------------------------------------------

typedef __attribute__((ext_vector_type(8))) short bf16x8;
typedef __attribute__((ext_vector_type(4))) float f32x4;

#define MFMA_BF16(a, b, c) __builtin_amdgcn_mfma_f32_16x16x32_bf16((a), (b), (c), 0, 0, 0)

__device__ __forceinline__ unsigned short f2bf(float f) {
  unsigned int u = __builtin_bit_cast(unsigned int, f);
  u += 0x7fffu + ((u >> 16) & 1u);  // RNE
  return (unsigned short)(u >> 16);
}
__device__ __forceinline__ unsigned int pack2(float a, float b) {
  return (unsigned int)f2bf(a) | ((unsigned int)f2bf(b) << 16);
}
__device__ __forceinline__ void gl16(const unsigned short* g, unsigned short* l) {
  __builtin_amdgcn_global_load_lds(
      (const __attribute__((address_space(1))) unsigned int*)g,
      (__attribute__((address_space(3))) unsigned int*)l, 16, 0, 0);
}

__global__ __launch_bounds__(256) void k_conv(const float* __restrict__ x,
                                              unsigned short* __restrict__ xb,
                                              const float* __restrict__ qkv_w,
                                              const float* __restrict__ proj_w,
                                              unsigned short* __restrict__ wbt) {
  const int gid = blockIdx.x * 256 + threadIdx.x;
  for (int u = gid; u < 3211264; u += 2048 * 256) {
    const float4 a = *reinterpret_cast<const float4*>(x + (size_t)u * 8);
    const float4 b = *reinterpret_cast<const float4*>(x + (size_t)u * 8 + 4);
    uint4 p;
    p.x = pack2(a.x, a.y); p.y = pack2(a.z, a.w);
    p.z = pack2(b.x, b.y); p.w = pack2(b.z, b.w);
    *reinterpret_cast<uint4*>(xb + (size_t)u * 8) = p;
  }
  if (gid < 32768) {  // 262144 weight f32, 8 per thread
    const float* s = (gid < 24576) ? qkv_w + (size_t)gid * 8
                                   : proj_w + (size_t)(gid - 24576) * 8;
    const float4 a = *reinterpret_cast<const float4*>(s);
    const float4 b = *reinterpret_cast<const float4*>(s + 4);
    uint4 p;
    p.x = pack2(a.x, a.y); p.y = pack2(a.z, a.w);
    p.z = pack2(b.x, b.y); p.w = pack2(b.z, b.w);
    *reinterpret_cast<uint4*>(wbt + (size_t)gid * 8) = p;
  }
}

// LDS chunk (row,slot) holds global colchunk g = slot ^ ((row>>1)&3).
#define GEMM_ISSUE(buf, kk)                                          \
  do {                                                               \
    gl16(gA + (kk) * 32,         As + (buf) * 4096 + t * 8);         \
    gl16(gA + (kk) * 32 + 16384, As + (buf) * 4096 + 2048 + t * 8);  \
    gl16(gB + (kk) * 32,         Bs + (buf) * 4096 + t * 8);         \
    gl16(gB + (kk) * 32 + 16384, Bs + (buf) * 4096 + 2048 + t * 8);  \
  } while (0)

#define GEMM_MAIN_LOOP()                                                         \
  GEMM_ISSUE(0, 0);                                                              \
  GEMM_ISSUE(1, 1);                                                              \
  for (int ks = 0; ks < 8; ++ks) {                                               \
    const int cur = ks & 1;                                                      \
    if (ks < 7) asm volatile("s_waitcnt vmcnt(4)" ::: "memory");                 \
    else        asm volatile("s_waitcnt vmcnt(0)" ::: "memory");                 \
    __builtin_amdgcn_s_barrier();                                                \
    const unsigned short* Ab = As + cur * 4096;                                  \
    const unsigned short* Bb = Bs + cur * 4096;                                  \
    bf16x8 af[4], bfr[4];                                                        \
    _Pragma("unroll") for (int i = 0; i < 4; ++i) {                              \
      const int ra = wr + i * 16 + l15;                                          \
      const int rb = wc + i * 16 + l15;                                          \
      af[i]  = *reinterpret_cast<const bf16x8*>(                                 \
          Ab + ra * 32 + ((l4 ^ ((ra >> 1) & 3)) * 8));                          \
      bfr[i] = *reinterpret_cast<const bf16x8*>(                                 \
          Bb + rb * 32 + ((l4 ^ ((rb >> 1) & 3)) * 8));                          \
    }                                                                            \
    asm volatile("s_waitcnt lgkmcnt(0)" ::: "memory");                           \
    __builtin_amdgcn_sched_barrier(0);                                           \
    __builtin_amdgcn_s_barrier();                                                \
    if (ks < 6) GEMM_ISSUE(cur, ks + 2);                                         \
    _Pragma("unroll") for (int mi = 0; mi < 4; ++mi)                             \
      _Pragma("unroll") for (int ni = 0; ni < 4; ++ni)                           \
        acc[mi][ni] = MFMA_BF16(af[mi], bfr[ni], acc[mi][ni]);                   \
  }

__global__ __launch_bounds__(256, 4) void k_qkv(const unsigned short* __restrict__ xb,
                                                const unsigned short* __restrict__ wbq,
                                                const float* __restrict__ bias,
                                                unsigned short* __restrict__ qkv) {
  __shared__ __align__(16) char lds[34816];
  unsigned short* As = (unsigned short*)lds;
  unsigned short* Bs = (unsigned short*)(lds + 16384);

  const int id = blockIdx.x;
  const int wg = (id & 7) * 588 + (id >> 3);
  const int mt = wg / 6, nt = wg - mt * 6;
  const int m0 = mt * 128, n0 = nt * 128;

  const int t = threadIdx.x, lane = t & 63, wid = t >> 6;
  const int wr = (wid >> 1) * 64, wc = (wid & 1) * 64;
  const int l15 = lane & 15, l4 = lane >> 4;

  float bv[4];
#pragma unroll
  for (int ni = 0; ni < 4; ++ni) bv[ni] = bias[n0 + wc + ni * 16 + l15];

  const int row0 = t >> 2, slot = t & 3;
  const int g = slot ^ ((row0 >> 1) & 3);
  const unsigned short* gA = xb  + (size_t)(m0 + row0) * 256 + g * 8;
  const unsigned short* gB = wbq + (size_t)(n0 + row0) * 256 + g * 8;

  f32x4 acc[4][4] = {};
  GEMM_MAIN_LOOP();

  unsigned short* Cst = (unsigned short*)lds;
#pragma unroll
  for (int mi = 0; mi < 4; ++mi)
#pragma unroll
    for (int ni = 0; ni < 4; ++ni)
#pragma unroll
      for (int r = 0; r < 4; ++r)
        Cst[(wr + mi * 16 + l4 * 4 + r) * 136 + wc + ni * 16 + l15] =
            f2bf(acc[mi][ni][r] + bv[ni]);
  __syncthreads();

  const int which = n0 >> 8;
  const int hbase = (n0 >> 5) & 7;
#pragma unroll
  for (int p = 0; p < 2; ++p) {
    const int pair = p * 256 + t;
    const int token = pair & 127, hidx = pair >> 7;
    const int mrow = m0 + token;
    const int b = mrow / 12544, pix = mrow - b * 12544;
    const int py = pix / 112, px = pix - py * 112;
    const int wy = py / 7, ty = py - wy * 7;
    const int wxx = px / 7, tx = px - wxx * 7;
    const int win = wy * 16 + wxx, tloc = ty * 7 + tx;
    const unsigned short* src = Cst + token * 136 + hidx * 32;
    unsigned short* dst = qkv +
        (((size_t)(b * 256 + win) * 3 + which) * 8 + hbase + hidx) * 1568 + tloc * 32;
#pragma unroll
    for (int c = 0; c < 4; ++c)
      *reinterpret_cast<uint4*>(dst + c * 8) = *reinterpret_cast<const uint4*>(src + c * 8);
  }
}

__global__ __launch_bounds__(64) void k_attn(const unsigned short* __restrict__ qkv,
                                             unsigned short* __restrict__ o) {
  __shared__ unsigned short vT[32 * 64];
  __shared__ unsigned short Pl[64 * 64];

  const int lane = threadIdx.x;
  const int l15 = lane & 15, l4 = lane >> 4;

  const int bid = blockIdx.x;
  const int h = bid & 7;
  const int bw = bid >> 3;
  const int b = bw >> 8, win = bw & 255;

  const unsigned short* qg = qkv + ((size_t)bw * 24 + h) * 1568;
  const unsigned short* kg = qkv + ((size_t)bw * 24 + 8 + h) * 1568;
  const unsigned short* vg = qkv + ((size_t)bw * 24 + 16 + h) * 1568;

#pragma unroll
  for (int it = 0; it < 4; ++it) {
    const int j = it * 16 + (lane >> 2), d0 = (lane & 3) * 8;
    uint4 vv = {0, 0, 0, 0};
    if (j < 49) vv = *reinterpret_cast<const uint4*>(vg + j * 32 + d0);
    union { uint4 v; unsigned short u[8]; } un; un.v = vv;
#pragma unroll
    for (int e = 0; e < 8; ++e) {
      const int d = d0 + e;
      vT[d * 64 + ((((j >> 3) ^ (d & 7)) << 3) | (j & 7))] = un.u[e];
    }
  }

  f32x4 s[4][4] = {};
  {
    bf16x8 kf[4];
#pragma unroll
    for (int nj = 0; nj < 4; ++nj)
      kf[nj] = *reinterpret_cast<const bf16x8*>(kg + (nj * 16 + l15) * 32 + l4 * 8);
#pragma unroll
    for (int mi = 0; mi < 4; ++mi) {
      const bf16x8 qf = *reinterpret_cast<const bf16x8*>(qg + (mi * 16 + l15) * 32 + l4 * 8);
#pragma unroll
      for (int nj = 0; nj < 4; ++nj)
        s[mi][nj] = MFMA_BF16(qf, kf[nj], s[mi][nj]);
    }
  }

  const float scale = 0.17677669529663687f;
#pragma unroll
  for (int mi = 0; mi < 4; ++mi) {
#pragma unroll
    for (int r = 0; r < 4; ++r) {
      float v[4]; float mx = -3.0e38f;
#pragma unroll
      for (int nj = 0; nj < 4; ++nj) {
        const int col = nj * 16 + l15;
        float sv = s[mi][nj][r] * scale;
        sv = (col < 49) ? sv : -3.0e38f;
        v[nj] = sv; mx = fmaxf(mx, sv);
      }
#pragma unroll
      for (int off = 1; off < 16; off <<= 1) mx = fmaxf(mx, __shfl_xor(mx, off));
      float e[4]; float sum = 0.f;
#pragma unroll
      for (int nj = 0; nj < 4; ++nj) { e[nj] = __expf(v[nj] - mx); sum += e[nj]; }
#pragma unroll
      for (int off = 1; off < 16; off <<= 1) sum += __shfl_xor(sum, off);
      const float inv = 1.0f / sum;
      const int row = mi * 16 + l4 * 4 + r;
#pragma unroll
      for (int nj = 0; nj < 4; ++nj) {
        const int col = nj * 16 + l15;
        Pl[row * 64 + ((((col >> 3) ^ (row & 7)) << 3) | (col & 7))] = f2bf(e[nj] * inv);
      }
    }
  }

  f32x4 oa[4][2] = {};
#pragma unroll
  for (int ksj = 0; ksj < 2; ++ksj) {
    const int chunk = ksj * 4 + l4;
    bf16x8 vb[2];
#pragma unroll
    for (int dt = 0; dt < 2; ++dt) {
      const int d = dt * 16 + l15;
      vb[dt] = *reinterpret_cast<const bf16x8*>(&vT[d * 64 + ((chunk ^ (d & 7)) << 3)]);
    }
#pragma unroll
    for (int mi = 0; mi < 4; ++mi) {
      const int row = mi * 16 + l15;
      const bf16x8 pa = *reinterpret_cast<const bf16x8*>(&Pl[row * 64 + ((chunk ^ (row & 7)) << 3)]);
#pragma unroll
      for (int dt = 0; dt < 2; ++dt)
        oa[mi][dt] = MFMA_BF16(pa, vb[dt], oa[mi][dt]);
    }
  }

  asm volatile("s_waitcnt lgkmcnt(0)" ::: "memory");
  __builtin_amdgcn_sched_barrier(0);
  unsigned short* Ost = Pl;
#pragma unroll
  for (int mi = 0; mi < 4; ++mi)
#pragma unroll
    for (int r = 0; r < 4; ++r) {
      const int i = mi * 16 + l4 * 4 + r;
#pragma unroll
      for (int dt = 0; dt < 2; ++dt)
        Ost[i * 40 + dt * 16 + l15] = f2bf(oa[mi][dt][r]);
    }

  const int wy = win >> 4, wx = win & 15;
  if (lane < 49) {
    const int ty = lane / 7, tx = lane - ty * 7;
    const size_t m = (size_t)b * 12544 + (size_t)(wy * 7 + ty) * 112 + (wx * 7 + tx);
    unsigned short* dst = o + m * 256 + h * 32;
#pragma unroll
    for (int c = 0; c < 4; ++c)
      *reinterpret_cast<uint4*>(dst + c * 8) =
          *reinterpret_cast<const uint4*>(Ost + lane * 40 + c * 8);
  }
}

__global__ __launch_bounds__(256, 4) void k_proj(const unsigned short* __restrict__ a,
                                                 const unsigned short* __restrict__ wbp,
                                                 const float* __restrict__ bias,
                                                 float* __restrict__ out) {
  __shared__ __align__(16) char lds[32768];
  unsigned short* As = (unsigned short*)lds;
  unsigned short* Bs = (unsigned short*)(lds + 16384);

  const int id = blockIdx.x;
  const int wg = (id & 7) * 196 + (id >> 3);
  const int mt = wg >> 1, nt = wg & 1;
  const int m0 = mt * 128, n0 = nt * 128;

  const int t = threadIdx.x, lane = t & 63, wid = t >> 6;
  const int wr = (wid >> 1) * 64, wc = (wid & 1) * 64;
  const int l15 = lane & 15, l4 = lane >> 4;

  float bv[4];
#pragma unroll
  for (int ni = 0; ni < 4; ++ni) bv[ni] = bias[n0 + wc + ni * 16 + l15];

  const int row0 = t >> 2, slot = t & 3;
  const int g = slot ^ ((row0 >> 1) & 3);
  const unsigned short* gA = a   + (size_t)(m0 + row0) * 256 + g * 8;
  const unsigned short* gB = wbp + (size_t)(n0 + row0) * 256 + g * 8;

  f32x4 acc[4][4] = {};
  GEMM_MAIN_LOOP();

#pragma unroll
  for (int mi = 0; mi < 4; ++mi)
#pragma unroll
    for (int r = 0; r < 4; ++r) {
      const int mrow = m0 + wr + mi * 16 + l4 * 4 + r;
      float* orow = out + (size_t)mrow * 256 + n0 + wc;
#pragma unroll
      for (int ni = 0; ni < 4; ++ni)
        orow[ni * 16 + l15] = acc[mi][ni][r] + bv[ni];
    }
}

extern "C" void kernel_launch(void* const* d_in, const int* in_sizes, int n_in,
                              void* d_out, int out_size, void* d_ws, size_t ws_size,
                              hipStream_t stream) {
  (void)in_sizes; (void)n_in; (void)out_size; (void)ws_size;
  const float* x      = (const float*)d_in[0];
  const float* qkv_w  = (const float*)d_in[1];
  const float* qkv_b  = (const float*)d_in[2];
  const float* proj_w = (const float*)d_in[3];
  const float* proj_b = (const float*)d_in[4];

  unsigned short* wsb  = (unsigned short*)d_ws;
  unsigned short* xb   = wsb;              // 25,690,112 bf16
  unsigned short* qkvg = wsb + 25690112;   // 77,070,336 bf16
  unsigned short* wbt  = wsb + 102760448;  // 262,144 bf16 weight table
  unsigned short* wbq  = wbt;              // qkv_w bf16 [768][256]
  unsigned short* wbp  = wbt + 196608;     // proj_w bf16 [256][256]
  unsigned short* ob   = xb;               // o aliases x_bf
  float* out = (float*)d_out;

  k_conv<<<dim3(2048),  dim3(256), 0, stream>>>(x, xb, qkv_w, proj_w, wbt);
  k_qkv <<<dim3(4704),  dim3(256), 0, stream>>>(xb, wbq, qkv_b, qkvg);
  k_attn<<<dim3(16384), dim3(64),  0, stream>>>(qkvg, ob);
  k_proj<<<dim3(1568),  dim3(256), 0, stream>>>(ob, wbp, proj_b, out);
}